// Round 2
// baseline (354.293 us; speedup 1.0000x reference)
//
#include <hip/hip_runtime.h>
#include <hip/hip_bf16.h>
#include <stdint.h>

// Problem constants
#define BB   2
#define SS   2048
#define HH   768
#define NHH  12
#define HDD  64
#define BSS  (BB*SS)          // 4096 rows

typedef unsigned short u16;
typedef unsigned int   u32;
typedef __attribute__((ext_vector_type(8))) short bf16x8_t;   // 8 bf16 (4 VGPRs) - MFMA A/B frag
typedef __attribute__((ext_vector_type(4))) float f32x4;      // MFMA C/D frag
typedef __attribute__((ext_vector_type(2))) u32   u32x2;
typedef __attribute__((ext_vector_type(4))) u32   u32x4;

__device__ __forceinline__ u16 f2b(float f) {   // round-to-nearest-even bf16
    u32 x; __builtin_memcpy(&x, &f, 4);
    u32 r = x + 0x7fffu + ((x >> 16) & 1u);
    return (u16)(r >> 16);
}

// ---------------------------------------------------------------------------
// Kernel 1: transpose fp32 768x768 weights -> bf16 Wt[n][k] so the GEMM
// stages both operands with contiguous 16B chunks (verified m92/m93 pattern).
// ---------------------------------------------------------------------------
__global__ __launch_bounds__(256) void transpose768(
    const float* __restrict__ Wq, const float* __restrict__ Wk,
    const float* __restrict__ Wv, const float* __restrict__ Wo,
    u16* __restrict__ out)
{
    int mat = blockIdx.z;
    const float* src = (mat == 0) ? Wq : (mat == 1) ? Wk : (mat == 2) ? Wv : Wo;
    u16* dst = out + (size_t)mat * 768 * 768;

    __shared__ float sm[64][68];  // +4 pad
    int r0 = blockIdx.y * 64, c0 = blockIdx.x * 64;
    int t = threadIdx.x;

    #pragma unroll
    for (int it = 0; it < 4; ++it) {            // 1024 float4 loads
        int c = t + it * 256;
        int r = c >> 4, sg = c & 15;
        *(float4*)&sm[r][sg * 4] = *(const float4*)&src[(size_t)(r0 + r) * 768 + c0 + sg * 4];
    }
    __syncthreads();
    #pragma unroll
    for (int it = 0; it < 2; ++it) {            // 512 x 8-bf16 stores
        int c = t + it * 256;
        int rr = c >> 3, sg = c & 7;
        u16 tmp[8] __attribute__((aligned(16)));
        #pragma unroll
        for (int j = 0; j < 8; ++j) tmp[j] = f2b(sm[sg * 8 + j][rr]);
        *(u32x4*)&dst[(size_t)(c0 + rr) * 768 + r0 + sg * 8] = *(u32x4*)tmp;
    }
}

// ---------------------------------------------------------------------------
// Kernel 2: pack int32 attention_mask (B,1,S,S) to a bitmask (1 MB, L2-resident)
// ---------------------------------------------------------------------------
__global__ __launch_bounds__(256) void maskpack(const int* __restrict__ mask,
                                                u32* __restrict__ bits)
{
    int w = blockIdx.x * 256 + threadIdx.x;     // 262144 words total
    const int4* p = (const int4*)(mask + (size_t)w * 32);
    u32 v = 0;
    #pragma unroll
    for (int i = 0; i < 8; ++i) {
        int4 m = p[i];
        v |= ((m.x != 0) ? 1u : 0u) << (4 * i + 0);
        v |= ((m.y != 0) ? 1u : 0u) << (4 * i + 1);
        v |= ((m.z != 0) ? 1u : 0u) << (4 * i + 2);
        v |= ((m.w != 0) ? 1u : 0u) << (4 * i + 3);
    }
    bits[w] = v;
}

// ---------------------------------------------------------------------------
// Kernel 3: y==0: LayerNorm(hidden) fp32 -> bf16 xln (wave per 768-row);
//           y==1: plain fp32 -> bf16 convert of cross_states.
// ---------------------------------------------------------------------------
__global__ __launch_bounds__(256) void lnorm_cvt(
    const float* __restrict__ hid, const float* __restrict__ cross,
    const float* __restrict__ g, const float* __restrict__ bb,
    u16* __restrict__ xln, u16* __restrict__ crossb)
{
    int wv = threadIdx.x >> 6, lane = threadIdx.x & 63;
    int row = blockIdx.x * 4 + wv;              // 4096 rows / 4 per block

    if (blockIdx.y == 1) {
        const float* xr = cross + (size_t)row * 768;
        u16* o = crossb + (size_t)row * 768;
        #pragma unroll
        for (int c = 0; c < 3; ++c) {
            float4 f = *(const float4*)&xr[c * 256 + lane * 4];
            u16 t4[4] __attribute__((aligned(8)));
            t4[0] = f2b(f.x); t4[1] = f2b(f.y); t4[2] = f2b(f.z); t4[3] = f2b(f.w);
            *(u32x2*)&o[c * 256 + lane * 4] = *(u32x2*)t4;
        }
        return;
    }

    const float* xr = hid + (size_t)row * 768;
    float v[12];
    float s = 0.f, s2 = 0.f;
    #pragma unroll
    for (int c = 0; c < 3; ++c) {
        float4 f = *(const float4*)&xr[c * 256 + lane * 4];
        v[c*4+0] = f.x; v[c*4+1] = f.y; v[c*4+2] = f.z; v[c*4+3] = f.w;
        s  += f.x + f.y + f.z + f.w;
        s2 += f.x*f.x + f.y*f.y + f.z*f.z + f.w*f.w;
    }
    #pragma unroll
    for (int off = 1; off < 64; off <<= 1) {
        s  += __shfl_xor(s,  off, 64);
        s2 += __shfl_xor(s2, off, 64);
    }
    float mu  = s  * (1.f / 768.f);
    float var = s2 * (1.f / 768.f) - mu * mu;
    float rs  = 1.f / sqrtf(var + 1e-5f);
    #pragma unroll
    for (int c = 0; c < 3; ++c) {
        float4 gg = *(const float4*)&g [c * 256 + lane * 4];
        float4 bv = *(const float4*)&bb[c * 256 + lane * 4];
        u16 o[4] __attribute__((aligned(8)));
        o[0] = f2b((v[c*4+0] - mu) * rs * gg.x + bv.x);
        o[1] = f2b((v[c*4+1] - mu) * rs * gg.y + bv.y);
        o[2] = f2b((v[c*4+2] - mu) * rs * gg.z + bv.z);
        o[3] = f2b((v[c*4+3] - mu) * rs * gg.w + bv.w);
        *(u32x2*)&xln[(size_t)row * 768 + c * 256 + lane * 4] = *(u32x2*)o;
    }
}

// ---------------------------------------------------------------------------
// Shared GEMM mainloop: C[128x128] += A[128xK] * Wt[128xK]^T, BK=32,
// 4 waves in 2x2, each wave 64x64 via 4x4 MFMA 16x16x32 accumulators.
// ---------------------------------------------------------------------------
__device__ __forceinline__ void gemm128_main(const u16* __restrict__ A,
                                             const u16* __restrict__ W,
                                             f32x4 acc[4][4])
{
    __shared__ u16 As[128][40];
    __shared__ u16 Bs[128][40];
    int m0 = blockIdx.x * 128, n0 = blockIdx.y * 128;
    int t = threadIdx.x;
    int wv = t >> 6, lane = t & 63, lm = lane & 15, quad = lane >> 4;
    int wr = wv >> 1, wc = wv & 1;

    for (int kt = 0; kt < 768 / 32; ++kt) {
        __syncthreads();                        // protect previous iter's reads
        #pragma unroll
        for (int it = 0; it < 2; ++it) {
            int c = t + it * 256, r = c >> 2, sg = c & 3;
            *(u32x4*)&As[r][sg * 8] = *(const u32x4*)&A[(size_t)(m0 + r) * 768 + kt * 32 + sg * 8];
            *(u32x4*)&Bs[r][sg * 8] = *(const u32x4*)&W[(size_t)(n0 + r) * 768 + kt * 32 + sg * 8];
        }
        __syncthreads();
        bf16x8_t af[4], bfv[4];
        #pragma unroll
        for (int i = 0; i < 4; ++i) af[i]  = *(const bf16x8_t*)&As[wr * 64 + i * 16 + lm][quad * 8];
        #pragma unroll
        for (int j = 0; j < 4; ++j) bfv[j] = *(const bf16x8_t*)&Bs[wc * 64 + j * 16 + lm][quad * 8];
        #pragma unroll
        for (int i = 0; i < 4; ++i)
            #pragma unroll
            for (int j = 0; j < 4; ++j)
                acc[i][j] = __builtin_amdgcn_mfma_f32_16x16x32_bf16(af[i], bfv[j], acc[i][j], 0, 0, 0);
    }
}

// ---------------------------------------------------------------------------
// Kernel 4: fused QKV projection. grid.z: 0=Q(from LN(x)), 1=K, 2=V.
// K/V add fp32 memory_tensors*0.5 in the epilogue; biases fp32.
// ---------------------------------------------------------------------------
__global__ __launch_bounds__(256) void qkv_gemm(
    const u16* __restrict__ xln, const u16* __restrict__ crossb,
    const u16* __restrict__ Wt,  const float* __restrict__ bq,
    const float* __restrict__ bk, const float* __restrict__ bv,
    const float* __restrict__ mem,
    u16* __restrict__ Qb, u16* __restrict__ Kb, u16* __restrict__ Vb)
{
    int z = blockIdx.z;
    const u16* A      = (z == 0) ? xln : crossb;
    const u16* W      = Wt + (size_t)z * 768 * 768;
    const float* bias = (z == 0) ? bq : (z == 1) ? bk : bv;
    u16* out          = (z == 0) ? Qb : (z == 1) ? Kb : Vb;
    const float* mp   = (z == 0) ? (const float*)nullptr : mem + (size_t)(z - 1) * BSS * HH;

    f32x4 z4 = {0.f, 0.f, 0.f, 0.f};
    f32x4 acc[4][4];
    #pragma unroll
    for (int i = 0; i < 4; ++i)
        #pragma unroll
        for (int j = 0; j < 4; ++j) acc[i][j] = z4;

    gemm128_main(A, W, acc);

    int t = threadIdx.x, wv = t >> 6, lane = t & 63, lm = lane & 15, quad = lane >> 4;
    int wr = wv >> 1, wc = wv & 1;
    int row0 = blockIdx.x * 128 + wr * 64 + quad * 4;  // C/D: row = quad*4+reg
    int col0 = blockIdx.y * 128 + wc * 64 + lm;        //      col = lane&15
    #pragma unroll
    for (int j = 0; j < 4; ++j) {
        int cg = col0 + j * 16;
        float bz = bias[cg];
        #pragma unroll
        for (int i = 0; i < 4; ++i) {
            int rg = row0 + i * 16;
            #pragma unroll
            for (int e = 0; e < 4; ++e) {
                float v = acc[i][j][e] + bz;
                if (mp) v += 0.5f * mp[(size_t)(rg + e) * HH + cg];
                out[(size_t)(rg + e) * HH + cg] = f2b(v);
            }
        }
    }
}

// ---------------------------------------------------------------------------
// Kernel 5: flash attention (bf16 in/out). Block = 4 waves, Q-tile = 64 rows
// (16/wave), K-tiles of 64, online softmax, P->A-operand via wave-private LDS.
// ---------------------------------------------------------------------------
__global__ __launch_bounds__(256) void attn_kernel(
    const u16* __restrict__ Q, const u16* __restrict__ K,
    const u16* __restrict__ V, const u32* __restrict__ mbits,
    u16* __restrict__ O)
{
    __shared__ u16   Ks[64][72];     // [k][d]
    __shared__ u16   Vt[64][72];     // [d][k]
    __shared__ short Ps[4][16][72];  // per-wave P transpose buffer

    int qt = blockIdx.x;             // 0..31 q-tiles
    int bh = blockIdx.y;             // 0..23
    int b = bh / NHH, h = bh % NHH;
    int t = threadIdx.x;
    int wv = t >> 6, lane = t & 63, lm = lane & 15, quad = lane >> 4;

    int qrow_g = b * SS + qt * 64 + wv * 16;     // wave's global Q row base
    const u16* qp = Q + (size_t)(qrow_g + lm) * HH + h * 64;
    bf16x8_t qf0 = *(const bf16x8_t*)&qp[quad * 8];        // A-frag, d in [0,32)
    bf16x8_t qf1 = *(const bf16x8_t*)&qp[32 + quad * 8];   // A-frag, d in [32,64)

    f32x4 z4 = {0.f, 0.f, 0.f, 0.f};
    f32x4 acc_o[4] = {z4, z4, z4, z4};
    float m_i[4], l_i[4];
    #pragma unroll
    for (int e = 0; e < 4; ++e) { m_i[e] = -3.0e38f; l_i[e] = 0.f; }

    const float SC = 0.18033688011112042f;       // log2(e)/sqrt(64)
    int kvrow0 = b * SS;
    int qloc = qt * 64 + wv * 16 + quad * 4;     // local q row for mask

    for (int kt = 0; kt < SS / 64; ++kt) {
        __syncthreads();
        // stage K tile [64][64]
        #pragma unroll
        for (int it = 0; it < 2; ++it) {
            int c = t + it * 256, r = c >> 3, sg = c & 7;
            *(u32x4*)&Ks[r][sg * 8] =
                *(const u32x4*)&K[(size_t)(kvrow0 + kt * 64 + r) * HH + h * 64 + sg * 8];
        }
        // stage V transposed: read 2 rows x 8 cols, write packed b32 pairs
        {
            int rp = t >> 3, sg = t & 7;
            const u16* vp = &V[(size_t)(kvrow0 + kt * 64 + 2 * rp) * HH + h * 64 + sg * 8];
            u32x4 va4 = *(const u32x4*)vp;
            u32x4 vb4 = *(const u32x4*)(vp + HH);
            u16 va[8] __attribute__((aligned(16)));
            u16 vb[8] __attribute__((aligned(16)));
            *(u32x4*)va = va4; *(u32x4*)vb = vb4;
            #pragma unroll
            for (int j = 0; j < 8; ++j) {
                u32 pr = (u32)va[j] | ((u32)vb[j] << 16);
                *((u32*)&Vt[sg * 8 + j][2 * rp]) = pr;
            }
        }
        __syncthreads();

        // scores: 16(q) x 64(k) per wave
        f32x4 sc[4];
        #pragma unroll
        for (int k16 = 0; k16 < 4; ++k16) {
            bf16x8_t kf0 = *(const bf16x8_t*)&Ks[k16 * 16 + lm][quad * 8];
            bf16x8_t kf1 = *(const bf16x8_t*)&Ks[k16 * 16 + lm][32 + quad * 8];
            f32x4 a = z4;
            a = __builtin_amdgcn_mfma_f32_16x16x32_bf16(qf0, kf0, a, 0, 0, 0);
            a = __builtin_amdgcn_mfma_f32_16x16x32_bf16(qf1, kf1, a, 0, 0, 0);
            sc[k16] = a * SC;
        }

        // mask (bitmask; fast path when 64-bit window is all ones)
        unsigned long long mw[4];
        bool allone = true;
        #pragma unroll
        for (int e = 0; e < 4; ++e) {
            u32x2 u = *(const u32x2*)&mbits[(size_t)(b * SS + qloc + e) * (SS / 32) + kt * 2];
            mw[e] = ((unsigned long long)u.y << 32) | (unsigned long long)u.x;
            allone = allone && (mw[e] == ~0ull);
        }
        if (!__all((int)allone)) {
            #pragma unroll
            for (int k16 = 0; k16 < 4; ++k16) {
                int kb = k16 * 16 + lm;
                #pragma unroll
                for (int e = 0; e < 4; ++e)
                    if (!((mw[e] >> kb) & 1ull)) sc[k16][e] = -3.0e38f;
            }
        }

        // online softmax
        float rmx[4];
        #pragma unroll
        for (int e = 0; e < 4; ++e)
            rmx[e] = fmaxf(fmaxf(sc[0][e], sc[1][e]), fmaxf(sc[2][e], sc[3][e]));
        #pragma unroll
        for (int off = 1; off < 16; off <<= 1) {
            #pragma unroll
            for (int e = 0; e < 4; ++e)
                rmx[e] = fmaxf(rmx[e], __shfl_xor(rmx[e], off, 64));
        }
        float alpha[4];
        #pragma unroll
        for (int e = 0; e < 4; ++e) {
            float mn = fmaxf(m_i[e], rmx[e]);
            alpha[e] = exp2f(m_i[e] - mn);
            m_i[e] = mn;
        }
        float rsum[4] = {0.f, 0.f, 0.f, 0.f};
        #pragma unroll
        for (int k16 = 0; k16 < 4; ++k16) {
            #pragma unroll
            for (int e = 0; e < 4; ++e) {
                float p = exp2f(sc[k16][e] - m_i[e]);
                sc[k16][e] = p;
                rsum[e] += p;
            }
        }
        #pragma unroll
        for (int off = 1; off < 16; off <<= 1) {
            #pragma unroll
            for (int e = 0; e < 4; ++e)
                rsum[e] += __shfl_xor(rsum[e], off, 64);
        }
        #pragma unroll
        for (int e = 0; e < 4; ++e) l_i[e] = l_i[e] * alpha[e] + rsum[e];
        #pragma unroll
        for (int j = 0; j < 4; ++j)
            #pragma unroll
            for (int e = 0; e < 4; ++e) acc_o[j][e] *= alpha[e];

        // P (C layout) -> A-operand layout via wave-private LDS round-trip
        #pragma unroll
        for (int k16 = 0; k16 < 4; ++k16)
            #pragma unroll
            for (int e = 0; e < 4; ++e)
                Ps[wv][quad * 4 + e][k16 * 16 + lm] = (short)f2b(sc[k16][e]);
        __asm__ volatile("" ::: "memory");   // order LDS write->read (same wave)

        // PV: acc_o[q][d] += P[q][k] * V[k][d]
        #pragma unroll
        for (int cc = 0; cc < 2; ++cc) {
            bf16x8_t pf = *(const bf16x8_t*)&Ps[wv][lm][cc * 32 + quad * 8];
            #pragma unroll
            for (int j = 0; j < 4; ++j) {
                bf16x8_t vf = *(const bf16x8_t*)&Vt[j * 16 + lm][cc * 32 + quad * 8];
                acc_o[j] = __builtin_amdgcn_mfma_f32_16x16x32_bf16(pf, vf, acc_o[j], 0, 0, 0);
            }
        }
    }

    // epilogue: O = acc_o / l
    float inv[4];
    #pragma unroll
    for (int e = 0; e < 4; ++e) inv[e] = 1.f / l_i[e];
    #pragma unroll
    for (int j = 0; j < 4; ++j)
        #pragma unroll
        for (int e = 0; e < 4; ++e)
            O[(size_t)(qrow_g + quad * 4 + e) * HH + h * 64 + j * 16 + lm] =
                f2b(acc_o[j][e] * inv[e]);
}

// ---------------------------------------------------------------------------
// Kernel 6: output projection + fp32 gate/gate_bias/dynamic_factor epilogue,
// fp32 output.
// ---------------------------------------------------------------------------
__global__ __launch_bounds__(256) void out_gemm(
    const u16* __restrict__ AO, const u16* __restrict__ Wt,
    const float* __restrict__ bo, const float* __restrict__ gate,
    const float* __restrict__ gbias, const float* __restrict__ dyn,
    float* __restrict__ out)
{
    f32x4 z4 = {0.f, 0.f, 0.f, 0.f};
    f32x4 acc[4][4];
    #pragma unroll
    for (int i = 0; i < 4; ++i)
        #pragma unroll
        for (int j = 0; j < 4; ++j) acc[i][j] = z4;

    gemm128_main(AO, Wt, acc);

    float gv = gate[0];
    float gb = gbias[0];
    int t = threadIdx.x, wv = t >> 6, lane = t & 63, lm = lane & 15, quad = lane >> 4;
    int wr = wv >> 1, wc = wv & 1;
    int row0 = blockIdx.x * 128 + wr * 64 + quad * 4;
    int col0 = blockIdx.y * 128 + wc * 64 + lm;
    #pragma unroll
    for (int j = 0; j < 4; ++j) {
        int cg = col0 + j * 16;
        float bz = bo[cg];
        #pragma unroll
        for (int i = 0; i < 4; ++i) {
            int rg = row0 + i * 16;
            #pragma unroll
            for (int e = 0; e < 4; ++e) {
                float v = acc[i][j][e] + bz;
                v = v * gv + gb;
                v *= dyn[rg + e];
                out[(size_t)(rg + e) * HH + cg] = v;
            }
        }
    }
}

// ---------------------------------------------------------------------------
extern "C" void kernel_launch(void* const* d_in, const int* in_sizes, int n_in,
                              void* d_out, int out_size, void* d_ws, size_t ws_size,
                              hipStream_t stream)
{
    (void)in_sizes; (void)n_in; (void)out_size; (void)ws_size;

    const float* hid   = (const float*)d_in[0];
    const float* cross = (const float*)d_in[1];
    const int*   amask = (const int*)d_in[2];
    const float* mem   = (const float*)d_in[3];
    const float* dyn   = (const float*)d_in[4];
    const float* Wq    = (const float*)d_in[5];
    const float* bq    = (const float*)d_in[6];
    const float* Wk    = (const float*)d_in[7];
    const float* bk    = (const float*)d_in[8];
    const float* Wv    = (const float*)d_in[9];
    const float* bv    = (const float*)d_in[10];
    const float* Wo    = (const float*)d_in[11];
    const float* bo    = (const float*)d_in[12];
    const float* gate  = (const float*)d_in[13];
    const float* gbias = (const float*)d_in[14];
    const float* lng   = (const float*)d_in[15];
    const float* lnb   = (const float*)d_in[16];

    // workspace layout (~37 MB; AO aliases xln — xln dead after qkv_gemm)
    char* p = (char*)d_ws;
    u16* Wt  = (u16*)p; p += (size_t)4 * 768 * 768 * 2;       // 4.72 MB
    u32* mb  = (u32*)p; p += (size_t)BB * SS * (SS / 32) * 4; // 1.05 MB
    u16* xln = (u16*)p; p += (size_t)BSS * HH * 2;            // 6.29 MB
    u16* crb = (u16*)p; p += (size_t)BSS * HH * 2;
    u16* Qb  = (u16*)p; p += (size_t)BSS * HH * 2;
    u16* Kb  = (u16*)p; p += (size_t)BSS * HH * 2;
    u16* Vb  = (u16*)p; p += (size_t)BSS * HH * 2;
    u16* AO  = xln;   // reuse

    transpose768<<<dim3(12, 12, 4), 256, 0, stream>>>(Wq, Wk, Wv, Wo, Wt);
    maskpack    <<<dim3(1024),      256, 0, stream>>>(amask, mb);
    lnorm_cvt   <<<dim3(1024, 2),   256, 0, stream>>>(hid, cross, lng, lnb, xln, crb);
    qkv_gemm    <<<dim3(32, 6, 3),  256, 0, stream>>>(xln, crb, Wt, bq, bk, bv, mem, Qb, Kb, Vb);
    attn_kernel <<<dim3(32, 24),    256, 0, stream>>>(Qb, Kb, Vb, mb, AO);
    out_gemm    <<<dim3(32, 6),     256, 0, stream>>>(AO, Wt + (size_t)3 * 768 * 768, bo,
                                                      gate, gbias, dyn, (float*)d_out);
}